// Round 9
// baseline (738.145 us; speedup 1.0000x reference)
//
#include <hip/hip_runtime.h>

// GCN 2-layer, atomic-free CSR build (counting sort via LDS histograms).
// Round-7 post-mortem: every GLOBAL atomic write-throughs a 32B sector to
// HBM (k_count: 6.4M atomics x 32B = 205MB at ~0.78TB/s = 274us; REP=8
// de-contention changed nothing). Fix: per-block LDS histograms + exact
// slot placement => zero global atomics in the entire pipeline.

#define NF 512
#define NH 16
#define NRANGE 8
#define NSLICE 32
#define RS 12500          // nodes per range = 100000/8 (n must be 8*RS)
#define XPAD 520

// ---- ws layout (4B units), total 9,901,056 floats = 39.6 MB ----
// dinv     @ 0        (n)
// ideg_tot @ 100000   (n)
// bsum     @ 200000   (1024)
// rowptr   @ 201024   (n+1)
// csr int2 @ 301056   (2*E)           byte off 1204224 %8==0
// partials @ 6701056  (NRANGE*NSLICE*RS = 3.2M) -- dead after k_fill2
// h        @ 6701056  (n*16)  overlays partials
// o1       @ 8301056  (n*16)  overlays partials

// Per-(range,slice) LDS histogram of dst. partials[bid*RS + b].
__global__ __launch_bounds__(256) void k_hist(const int* __restrict__ dst,
                                              int* __restrict__ partials, int E) {
    __shared__ int hist[RS];
    int r = blockIdx.x >> 5, s = blockIdx.x & 31;
    for (int t = threadIdx.x; t < RS; t += 256) hist[t] = 0;
    __syncthreads();
    int lo = r * RS;
    int ss = (E + NSLICE - 1) / NSLICE;
    int e0 = s * ss, e1 = min(e0 + ss, E);
    for (int e = e0 + threadIdx.x; e < e1; e += 256) {
        unsigned ld = (unsigned)(dst[e] - lo);
        if (ld < (unsigned)RS) atomicAdd(&hist[ld], 1);
    }
    __syncthreads();
    int* pp = partials + (size_t)blockIdx.x * RS;
    for (int t = threadIdx.x; t < RS; t += 256) pp[t] = hist[t];
}

// ideg_tot[d] = sum over slices of partials
__global__ __launch_bounds__(256) void k_sumdeg(const int* __restrict__ partials,
                                                int* __restrict__ ideg, int n) {
    int d = blockIdx.x * 256 + threadIdx.x;
    if (d >= n) return;
    int r = d / RS, b = d - r * RS;
    const int* p = partials + (size_t)(r * NSLICE) * RS + b;
    int acc = 0;
#pragma unroll
    for (int s = 0; s < NSLICE; ++s) acc += p[s * RS];
    ideg[d] = acc;
}

// exclusive scan of ideg_tot -> rowptr (verified rounds 6-7)
__global__ __launch_bounds__(256) void k_scan_block(const int* __restrict__ ideg,
                                                    int* __restrict__ rowptr,
                                                    int* __restrict__ bsum, int n) {
    __shared__ int sh[256];
    int t = threadIdx.x, g = blockIdx.x * 256 + t;
    int v = (g < n) ? ideg[g] : 0;
    sh[t] = v; __syncthreads();
    for (int off = 1; off < 256; off <<= 1) {
        int a = (t >= off) ? sh[t - off] : 0;
        __syncthreads();
        sh[t] += a;
        __syncthreads();
    }
    if (g < n) rowptr[g] = sh[t] - v;
    if (t == 255) bsum[blockIdx.x] = sh[255];
}

__global__ __launch_bounds__(512) void k_scan_tops(int* __restrict__ bsum,
                                                   int* __restrict__ rowptr,
                                                   int nb, int n) {
    __shared__ int sh[512];
    int t = threadIdx.x;
    int v = (t < nb) ? bsum[t] : 0;
    sh[t] = v; __syncthreads();
    for (int off = 1; off < 512; off <<= 1) {
        int a = (t >= off) ? sh[t - off] : 0;
        __syncthreads();
        sh[t] += a;
        __syncthreads();
    }
    if (t < nb) bsum[t] = sh[t] - v;
    if (t == 511) rowptr[n] = sh[511];     // == E
}

__global__ __launch_bounds__(256) void k_scan_add(int* __restrict__ rowptr,
                                                  const int* __restrict__ bsum, int n) {
    int i = blockIdx.x * 256 + threadIdx.x;
    if (i < n) rowptr[i] += bsum[i >> 8];
}

// partials: per-slice counts -> exact slot starts (prefix over slices)
__global__ __launch_bounds__(256) void k_slicecur(int* __restrict__ partials,
                                                  const int* __restrict__ rowptr, int n) {
    int d = blockIdx.x * 256 + threadIdx.x;
    if (d >= n) return;
    int r = d / RS, b = d - r * RS;
    int* p = partials + (size_t)(r * NSLICE) * RS + b;
    int run = rowptr[d];
#pragma unroll
    for (int s = 0; s < NSLICE; ++s) {
        int c = p[s * RS];
        p[s * RS] = run;
        run += c;
    }
}

// place edges at exact csr positions; cursors live in LDS only
__global__ __launch_bounds__(256) void k_fill2(const int* __restrict__ src,
                                               const int* __restrict__ dst,
                                               const float* __restrict__ ew,
                                               const int* __restrict__ partials,
                                               int2* __restrict__ csr, int E) {
    __shared__ int cur[RS];
    int r = blockIdx.x >> 5, s = blockIdx.x & 31;
    const int* cp = partials + (size_t)blockIdx.x * RS;
    for (int t = threadIdx.x; t < RS; t += 256) cur[t] = cp[t];
    __syncthreads();
    int lo = r * RS;
    int ss = (E + NSLICE - 1) / NSLICE;
    int e0 = s * ss, e1 = min(e0 + ss, E);
    for (int e = e0 + threadIdx.x; e < e1; e += 256) {
        unsigned ld = (unsigned)(dst[e] - lo);
        if (ld < (unsigned)RS) {
            int pos = atomicAdd(&cur[ld], 1);
            csr[pos] = make_int2(src[e], __float_as_int(ew[e]));
        }
    }
}

// dinv[d] = rsqrt(1 + sum of ew over csr row d); 16 lanes/node + shfl reduce
__global__ __launch_bounds__(256) void k_wdeg(const int2* __restrict__ csr,
                                              const int* __restrict__ rowptr,
                                              float* __restrict__ dinv, int n) {
    int tid = blockIdx.x * 256 + threadIdx.x;
    int d = tid >> 4, f = tid & 15;
    if (d >= n) return;
    int e0 = rowptr[d], e1 = rowptr[d + 1];
    float w = 0.0f;
    for (int j = e0 + f; j < e1; j += 16) w += __int_as_float(csr[j].y);
#pragma unroll
    for (int o = 8; o; o >>= 1) w += __shfl_xor(w, o, 16);
    if (f == 0) dinv[d] = rsqrtf(1.0f + w);
}

// h = x @ W1, 16 rows/block; x staged via coalesced float4; W1 in k4-blocked
// LDS layout wt[k4][f][4] (16-lane b128 read = 64 consecutive floats, free).
__global__ __launch_bounds__(256) void k_gemm1(const float* __restrict__ x,
                                               const float* __restrict__ w1,
                                               float* __restrict__ h) {
    __shared__ float xs[16 * XPAD];
    __shared__ float wt[NF * NH];
    for (int t = threadIdx.x; t < NF * NH; t += 256) {
        int k = t >> 4, f = t & 15;
        wt[(k >> 2) * 64 + (f << 2) + (k & 3)] = w1[t];
    }
    const float4* xsrc = (const float4*)(x + (size_t)blockIdx.x * 16 * NF);
#pragma unroll
    for (int s = 0; s < 8; ++s) {
        int idx = s * 256 + threadIdx.x;
        int row = idx >> 7, col4 = idx & 127;
        float4 v = xsrc[idx];
        float* p = &xs[row * XPAD + col4 * 4];
        p[0] = v.x; p[1] = v.y; p[2] = v.z; p[3] = v.w;
    }
    __syncthreads();
    int r = threadIdx.x >> 4, f = threadIdx.x & 15;
    const float4* xr = (const float4*)&xs[r * XPAD];
    const float4* wr = (const float4*)&wt[f << 2];
    float acc = 0.0f;
#pragma unroll 8
    for (int k4 = 0; k4 < NF / 4; ++k4) {
        float4 a = xr[k4], b = wr[k4 * 16];
        acc = fmaf(a.x, b.x, acc);
        acc = fmaf(a.y, b.y, acc);
        acc = fmaf(a.z, b.z, acc);
        acc = fmaf(a.w, b.w, acc);
    }
    h[(size_t)(blockIdx.x * 16 + r) * NH + f] = acc;
}

// out[d] = in[d]*dinv[d]^2 + sum in[s]*dinv[s]*ew*dinv[d]; nrm inline
__global__ __launch_bounds__(256) void k_gather(const float* __restrict__ in,
                                                const float* __restrict__ dinv,
                                                const int* __restrict__ rowptr,
                                                const int2* __restrict__ csr,
                                                float* __restrict__ out, int n) {
    int tid = blockIdx.x * 256 + threadIdx.x;
    int d = tid >> 4, f = tid & 15;
    if (d >= n) return;
    float di = dinv[d];
    float acc = in[tid] * di * di;
    int e0 = rowptr[d], e1 = rowptr[d + 1];
    for (int j = e0; j < e1; ++j) {
        int2 ent = csr[j];                         // broadcast across 16 lanes
        float nrm = dinv[ent.x] * __int_as_float(ent.y) * di;   // L2-resident
        acc = fmaf(in[ent.x * NH + f], nrm, acc);
    }
    out[tid] = acc;
}

__global__ __launch_bounds__(256) void k_biasrelu(float* __restrict__ o1,
                                                  const float* __restrict__ b1, int n16) {
    int tid = blockIdx.x * 256 + threadIdx.x;
    if (tid < n16) o1[tid] = fmaxf(o1[tid] + b1[tid & 15], 0.0f);
}

__global__ __launch_bounds__(256) void k_out(const float* __restrict__ agg,
                                             const float* __restrict__ w2,
                                             const float* __restrict__ b2,
                                             float* __restrict__ out, int n) {
    __shared__ float w2s[NH * 40];
    __shared__ float b2s[40];
    for (int t = threadIdx.x; t < NH * 40; t += 256) w2s[t] = w2[t];
    if (threadIdx.x < 40) b2s[threadIdx.x] = b2[threadIdx.x];
    __syncthreads();
    int i = blockIdx.x * 256 + threadIdx.x;
    if (i >= n) return;
    float v[NH];
    const float4* ap = (const float4*)(agg + (size_t)i * NH);
#pragma unroll
    for (int m = 0; m < 4; ++m) {
        float4 t4 = ap[m];
        v[4 * m] = t4.x; v[4 * m + 1] = t4.y; v[4 * m + 2] = t4.z; v[4 * m + 3] = t4.w;
    }
    float z[40];
#pragma unroll
    for (int c = 0; c < 40; ++c) {
        float a = b2s[c];
#pragma unroll
        for (int ff = 0; ff < NH; ++ff) a = fmaf(v[ff], w2s[ff * 40 + c], a);
        z[c] = a;
    }
    float mx = z[0];
#pragma unroll
    for (int c = 1; c < 40; ++c) mx = fmaxf(mx, z[c]);
    float sum = 0.0f;
#pragma unroll
    for (int c = 0; c < 40; ++c) sum += expf(z[c] - mx);
    float ls = mx + logf(sum);
    float4* op = (float4*)(out + (size_t)i * 40);
#pragma unroll
    for (int m = 0; m < 10; ++m) {
        float4 o;
        o.x = z[4 * m] - ls; o.y = z[4 * m + 1] - ls;
        o.z = z[4 * m + 2] - ls; o.w = z[4 * m + 3] - ls;
        op[m] = o;
    }
}

extern "C" void kernel_launch(void* const* d_in, const int* in_sizes, int n_in,
                              void* d_out, int out_size, void* d_ws, size_t ws_size,
                              hipStream_t stream) {
    const float* x  = (const float*)d_in[0];
    const int*   ei = (const int*)d_in[1];
    const float* ew = (const float*)d_in[2];
    const float* w1 = (const float*)d_in[3];
    const float* b1 = (const float*)d_in[4];
    const float* w2 = (const float*)d_in[5];
    const float* b2 = (const float*)d_in[6];
    float* out = (float*)d_out;

    int n = in_sizes[0] / NF;      // 100000 (= NRANGE*RS)
    int E = in_sizes[2];           // 3200000
    const int* src = ei;
    const int* dst = ei + E;

    float* ws       = (float*)d_ws;
    float* dinv     = ws;                       // n
    int*   ideg_tot = (int*)(ws + 100000);      // n
    int*   bsum     = (int*)(ws + 200000);      // 1024
    int*   rowptr   = (int*)(ws + 201024);      // n+1
    int2*  csr      = (int2*)(ws + 301056);     // 2*E ints
    int*   partials = (int*)(ws + 6701056);     // 3.2M, dead after k_fill2
    float* h        = ws + 6701056;             // overlays partials
    float* o1       = ws + 8301056;             // overlays partials

    int nb_n  = (n + 255) / 256;                // 391
    int nb_nf = (n * NH + 255) / 256;           // 6250

    k_hist<<<NRANGE * NSLICE, 256, 0, stream>>>(dst, partials, E);
    k_sumdeg<<<nb_n, 256, 0, stream>>>(partials, ideg_tot, n);
    k_scan_block<<<nb_n, 256, 0, stream>>>(ideg_tot, rowptr, bsum, n);
    k_scan_tops<<<1, 512, 0, stream>>>(bsum, rowptr, nb_n, n);
    k_scan_add<<<nb_n, 256, 0, stream>>>(rowptr, bsum, n);
    k_slicecur<<<nb_n, 256, 0, stream>>>(partials, rowptr, n);
    k_fill2<<<NRANGE * NSLICE, 256, 0, stream>>>(src, dst, ew, partials, csr, E);
    k_wdeg<<<nb_nf, 256, 0, stream>>>(csr, rowptr, dinv, n);
    k_gemm1<<<n / 16, 256, 0, stream>>>(x, w1, h);
    k_gather<<<nb_nf, 256, 0, stream>>>(h, dinv, rowptr, csr, o1, n);
    k_biasrelu<<<nb_nf, 256, 0, stream>>>(o1, b1, n * NH);
    k_gather<<<nb_nf, 256, 0, stream>>>(o1, dinv, rowptr, csr, h, n);
    k_out<<<nb_n, 256, 0, stream>>>(h, w2, b2, out, n);
}

// Round 10
// 667.368 us; speedup vs baseline: 1.1061x; 1.1061x over previous
//
#include <hip/hip_runtime.h>

// GCN 2-layer, atomic-free CSR build (counting sort via LDS histograms).
// Round-9 post-mortem: k_fill2 was 337us at 11.5% occupancy -- 256-block
// grid = 1 block/CU = 1 wave/SIMD, pure load-latency serialization (only
// 130MB moved; 385 GB/s; VALUBusy 2%). Fix: NRANGE 8->32 (RS 3125), grid
// 1024 blocks, LDS 12.5KB -> 4-8 blocks/CU. partials = NSLICE*n unchanged.
// Block order s-major so the 32 blocks sharing an edge slice hit L2.

#define NF 512
#define NH 16
#define NRANGE 32
#define NSLICE 32
#define RS 3125           // nodes per range = 100000/32
#define XPAD 520

// ---- ws layout (4B units), total 9,901,056 floats = 39.6 MB ----
// dinv     @ 0        (n)
// ideg_tot @ 100000   (n)
// bsum     @ 200000   (1024)
// rowptr   @ 201024   (n+1)
// csr int2 @ 301056   (2*E)           byte off 1204224 %8==0
// partials @ 6701056  (NSLICE*n = 3.2M) -- dead after k_fill2
// h        @ 6701056  (n*16)  overlays partials
// o1       @ 8301056  (n*16)  overlays partials

// Per-(range,slice) LDS histogram of dst. bid = s*NRANGE + r.
// partials[(r*NSLICE + s)*RS + b].
__global__ __launch_bounds__(256) void k_hist(const int* __restrict__ dst,
                                              int* __restrict__ partials, int E) {
    __shared__ int hist[RS];
    int r = blockIdx.x & (NRANGE - 1), s = blockIdx.x >> 5;
    for (int t = threadIdx.x; t < RS; t += 256) hist[t] = 0;
    __syncthreads();
    int lo = r * RS;
    int ss = (E + NSLICE - 1) / NSLICE;
    int e0 = s * ss, e1 = min(e0 + ss, E);
    for (int e = e0 + threadIdx.x; e < e1; e += 256) {
        unsigned ld = (unsigned)(dst[e] - lo);
        if (ld < (unsigned)RS) atomicAdd(&hist[ld], 1);
    }
    __syncthreads();
    int* pp = partials + (size_t)(r * NSLICE + s) * RS;
    for (int t = threadIdx.x; t < RS; t += 256) pp[t] = hist[t];
}

// ideg_tot[d] = sum over slices of partials
__global__ __launch_bounds__(256) void k_sumdeg(const int* __restrict__ partials,
                                                int* __restrict__ ideg, int n) {
    int d = blockIdx.x * 256 + threadIdx.x;
    if (d >= n) return;
    int r = d / RS, b = d - r * RS;
    const int* p = partials + (size_t)(r * NSLICE) * RS + b;
    int acc = 0;
#pragma unroll
    for (int s = 0; s < NSLICE; ++s) acc += p[s * RS];
    ideg[d] = acc;
}

// exclusive scan of ideg_tot -> rowptr (verified rounds 6-9)
__global__ __launch_bounds__(256) void k_scan_block(const int* __restrict__ ideg,
                                                    int* __restrict__ rowptr,
                                                    int* __restrict__ bsum, int n) {
    __shared__ int sh[256];
    int t = threadIdx.x, g = blockIdx.x * 256 + t;
    int v = (g < n) ? ideg[g] : 0;
    sh[t] = v; __syncthreads();
    for (int off = 1; off < 256; off <<= 1) {
        int a = (t >= off) ? sh[t - off] : 0;
        __syncthreads();
        sh[t] += a;
        __syncthreads();
    }
    if (g < n) rowptr[g] = sh[t] - v;
    if (t == 255) bsum[blockIdx.x] = sh[255];
}

__global__ __launch_bounds__(512) void k_scan_tops(int* __restrict__ bsum,
                                                   int* __restrict__ rowptr,
                                                   int nb, int n) {
    __shared__ int sh[512];
    int t = threadIdx.x;
    int v = (t < nb) ? bsum[t] : 0;
    sh[t] = v; __syncthreads();
    for (int off = 1; off < 512; off <<= 1) {
        int a = (t >= off) ? sh[t - off] : 0;
        __syncthreads();
        sh[t] += a;
        __syncthreads();
    }
    if (t < nb) bsum[t] = sh[t] - v;
    if (t == 511) rowptr[n] = sh[511];     // == E
}

__global__ __launch_bounds__(256) void k_scan_add(int* __restrict__ rowptr,
                                                  const int* __restrict__ bsum, int n) {
    int i = blockIdx.x * 256 + threadIdx.x;
    if (i < n) rowptr[i] += bsum[i >> 8];
}

// partials: per-slice counts -> exact slot starts (prefix over slices)
__global__ __launch_bounds__(256) void k_slicecur(int* __restrict__ partials,
                                                  const int* __restrict__ rowptr, int n) {
    int d = blockIdx.x * 256 + threadIdx.x;
    if (d >= n) return;
    int r = d / RS, b = d - r * RS;
    int* p = partials + (size_t)(r * NSLICE) * RS + b;
    int run = rowptr[d];
#pragma unroll
    for (int s = 0; s < NSLICE; ++s) {
        int c = p[s * RS];
        p[s * RS] = run;
        run += c;
    }
}

// place edges at exact csr positions; cursors live in LDS only
__global__ __launch_bounds__(256) void k_fill2(const int* __restrict__ src,
                                               const int* __restrict__ dst,
                                               const float* __restrict__ ew,
                                               const int* __restrict__ partials,
                                               int2* __restrict__ csr, int E) {
    __shared__ int cur[RS];
    int r = blockIdx.x & (NRANGE - 1), s = blockIdx.x >> 5;
    const int* cp = partials + (size_t)(r * NSLICE + s) * RS;
    for (int t = threadIdx.x; t < RS; t += 256) cur[t] = cp[t];
    __syncthreads();
    int lo = r * RS;
    int ss = (E + NSLICE - 1) / NSLICE;
    int e0 = s * ss, e1 = min(e0 + ss, E);
    for (int e = e0 + threadIdx.x; e < e1; e += 256) {
        unsigned ld = (unsigned)(dst[e] - lo);
        if (ld < (unsigned)RS) {
            int pos = atomicAdd(&cur[ld], 1);
            csr[pos] = make_int2(src[e], __float_as_int(ew[e]));
        }
    }
}

// dinv[d] = rsqrt(1 + sum of ew over csr row d); 16 lanes/node + shfl reduce
__global__ __launch_bounds__(256) void k_wdeg(const int2* __restrict__ csr,
                                              const int* __restrict__ rowptr,
                                              float* __restrict__ dinv, int n) {
    int tid = blockIdx.x * 256 + threadIdx.x;
    int d = tid >> 4, f = tid & 15;
    if (d >= n) return;
    int e0 = rowptr[d], e1 = rowptr[d + 1];
    float w = 0.0f;
    for (int j = e0 + f; j < e1; j += 16) w += __int_as_float(csr[j].y);
#pragma unroll
    for (int o = 8; o; o >>= 1) w += __shfl_xor(w, o, 16);
    if (f == 0) dinv[d] = rsqrtf(1.0f + w);
}

// h = x @ W1, 16 rows/block; x staged via coalesced float4; W1 in k4-blocked
// LDS layout wt[k4][f][4] (16-lane b128 read = 64 consecutive floats, free).
__global__ __launch_bounds__(256) void k_gemm1(const float* __restrict__ x,
                                               const float* __restrict__ w1,
                                               float* __restrict__ h) {
    __shared__ float xs[16 * XPAD];
    __shared__ float wt[NF * NH];
    for (int t = threadIdx.x; t < NF * NH; t += 256) {
        int k = t >> 4, f = t & 15;
        wt[(k >> 2) * 64 + (f << 2) + (k & 3)] = w1[t];
    }
    const float4* xsrc = (const float4*)(x + (size_t)blockIdx.x * 16 * NF);
#pragma unroll
    for (int s = 0; s < 8; ++s) {
        int idx = s * 256 + threadIdx.x;
        int row = idx >> 7, col4 = idx & 127;
        float4 v = xsrc[idx];
        float* p = &xs[row * XPAD + col4 * 4];
        p[0] = v.x; p[1] = v.y; p[2] = v.z; p[3] = v.w;
    }
    __syncthreads();
    int r = threadIdx.x >> 4, f = threadIdx.x & 15;
    const float4* xr = (const float4*)&xs[r * XPAD];
    const float4* wr = (const float4*)&wt[f << 2];
    float acc = 0.0f;
#pragma unroll 8
    for (int k4 = 0; k4 < NF / 4; ++k4) {
        float4 a = xr[k4], b = wr[k4 * 16];
        acc = fmaf(a.x, b.x, acc);
        acc = fmaf(a.y, b.y, acc);
        acc = fmaf(a.z, b.z, acc);
        acc = fmaf(a.w, b.w, acc);
    }
    h[(size_t)(blockIdx.x * 16 + r) * NH + f] = acc;
}

// out[d] = in[d]*dinv[d]^2 + sum in[s]*dinv[s]*ew*dinv[d]; nrm inline
__global__ __launch_bounds__(256) void k_gather(const float* __restrict__ in,
                                                const float* __restrict__ dinv,
                                                const int* __restrict__ rowptr,
                                                const int2* __restrict__ csr,
                                                float* __restrict__ out, int n) {
    int tid = blockIdx.x * 256 + threadIdx.x;
    int d = tid >> 4, f = tid & 15;
    if (d >= n) return;
    float di = dinv[d];
    float acc = in[tid] * di * di;
    int e0 = rowptr[d], e1 = rowptr[d + 1];
    for (int j = e0; j < e1; ++j) {
        int2 ent = csr[j];                         // broadcast across 16 lanes
        float nrm = dinv[ent.x] * __int_as_float(ent.y) * di;   // L2-resident
        acc = fmaf(in[ent.x * NH + f], nrm, acc);
    }
    out[tid] = acc;
}

__global__ __launch_bounds__(256) void k_biasrelu(float* __restrict__ o1,
                                                  const float* __restrict__ b1, int n16) {
    int tid = blockIdx.x * 256 + threadIdx.x;
    if (tid < n16) o1[tid] = fmaxf(o1[tid] + b1[tid & 15], 0.0f);
}

__global__ __launch_bounds__(256) void k_out(const float* __restrict__ agg,
                                             const float* __restrict__ w2,
                                             const float* __restrict__ b2,
                                             float* __restrict__ out, int n) {
    __shared__ float w2s[NH * 40];
    __shared__ float b2s[40];
    for (int t = threadIdx.x; t < NH * 40; t += 256) w2s[t] = w2[t];
    if (threadIdx.x < 40) b2s[threadIdx.x] = b2[threadIdx.x];
    __syncthreads();
    int i = blockIdx.x * 256 + threadIdx.x;
    if (i >= n) return;
    float v[NH];
    const float4* ap = (const float4*)(agg + (size_t)i * NH);
#pragma unroll
    for (int m = 0; m < 4; ++m) {
        float4 t4 = ap[m];
        v[4 * m] = t4.x; v[4 * m + 1] = t4.y; v[4 * m + 2] = t4.z; v[4 * m + 3] = t4.w;
    }
    float z[40];
#pragma unroll
    for (int c = 0; c < 40; ++c) {
        float a = b2s[c];
#pragma unroll
        for (int ff = 0; ff < NH; ++ff) a = fmaf(v[ff], w2s[ff * 40 + c], a);
        z[c] = a;
    }
    float mx = z[0];
#pragma unroll
    for (int c = 1; c < 40; ++c) mx = fmaxf(mx, z[c]);
    float sum = 0.0f;
#pragma unroll
    for (int c = 0; c < 40; ++c) sum += expf(z[c] - mx);
    float ls = mx + logf(sum);
    float4* op = (float4*)(out + (size_t)i * 40);
#pragma unroll
    for (int m = 0; m < 10; ++m) {
        float4 o;
        o.x = z[4 * m] - ls; o.y = z[4 * m + 1] - ls;
        o.z = z[4 * m + 2] - ls; o.w = z[4 * m + 3] - ls;
        op[m] = o;
    }
}

extern "C" void kernel_launch(void* const* d_in, const int* in_sizes, int n_in,
                              void* d_out, int out_size, void* d_ws, size_t ws_size,
                              hipStream_t stream) {
    const float* x  = (const float*)d_in[0];
    const int*   ei = (const int*)d_in[1];
    const float* ew = (const float*)d_in[2];
    const float* w1 = (const float*)d_in[3];
    const float* b1 = (const float*)d_in[4];
    const float* w2 = (const float*)d_in[5];
    const float* b2 = (const float*)d_in[6];
    float* out = (float*)d_out;

    int n = in_sizes[0] / NF;      // 100000 (= NRANGE*RS)
    int E = in_sizes[2];           // 3200000
    const int* src = ei;
    const int* dst = ei + E;

    float* ws       = (float*)d_ws;
    float* dinv     = ws;                       // n
    int*   ideg_tot = (int*)(ws + 100000);      // n
    int*   bsum     = (int*)(ws + 200000);      // 1024
    int*   rowptr   = (int*)(ws + 201024);      // n+1
    int2*  csr      = (int2*)(ws + 301056);     // 2*E ints
    int*   partials = (int*)(ws + 6701056);     // 3.2M, dead after k_fill2
    float* h        = ws + 6701056;             // overlays partials
    float* o1       = ws + 8301056;             // overlays partials

    int nb_n  = (n + 255) / 256;                // 391
    int nb_nf = (n * NH + 255) / 256;           // 6250

    k_hist<<<NRANGE * NSLICE, 256, 0, stream>>>(dst, partials, E);
    k_sumdeg<<<nb_n, 256, 0, stream>>>(partials, ideg_tot, n);
    k_scan_block<<<nb_n, 256, 0, stream>>>(ideg_tot, rowptr, bsum, n);
    k_scan_tops<<<1, 512, 0, stream>>>(bsum, rowptr, nb_n, n);
    k_scan_add<<<nb_n, 256, 0, stream>>>(rowptr, bsum, n);
    k_slicecur<<<nb_n, 256, 0, stream>>>(partials, rowptr, n);
    k_fill2<<<NRANGE * NSLICE, 256, 0, stream>>>(src, dst, ew, partials, csr, E);
    k_wdeg<<<nb_nf, 256, 0, stream>>>(csr, rowptr, dinv, n);
    k_gemm1<<<n / 16, 256, 0, stream>>>(x, w1, h);
    k_gather<<<nb_nf, 256, 0, stream>>>(h, dinv, rowptr, csr, o1, n);
    k_biasrelu<<<nb_nf, 256, 0, stream>>>(o1, b1, n * NH);
    k_gather<<<nb_nf, 256, 0, stream>>>(o1, dinv, rowptr, csr, h, n);
    k_out<<<nb_n, 256, 0, stream>>>(h, w2, b2, out, n);
}

// Round 12
// 414.288 us; speedup vs baseline: 1.7817x; 1.6109x over previous
//
#include <hip/hip_runtime.h>

// GCN 2-layer. Round-10 post-mortem: hist/fill2 re-scan the full edge list
// once per 32-node-range => 32x redundant reads (1.2GB L2 traffic), 3% keep
// rate. Fix: two-level binning. (1) count edges per (bucket, block) +
// exact scan => atomic-free binfill writes each edge ONCE into its range
// bucket (packed src|dst_local + ew). (2) per-range hist/fill read only
// their own bucket. Zero global atomics. Build traffic ~130MB total.

#define NF 512
#define NH 16
#define NRANGE 32
#define NS2 8
#define RS 3125           // nodes per range = 100000/32
#define EB 1024           // edges per bin block
#define XPAD 520

// ---- ws layout (4B units), total 14,002,112 = 56.0 MB ----
// dinv @0 (100000) | ideg @100000 (100000) | bsum @200000 (1024)
// rowptr @201024 (100001, pad->301056) | bsum2 @301056 (1024)
// bktcnt @302080 (100032, scanned in place) | partials @402112 (NS2*n)
// csr int2 @1202112 (2E) | bpack @7602112 (E) | bew @10802112 (E)
// h @7602112 overlays bpack | o1 @9202112 overlays bpack

__global__ __launch_bounds__(256) void k_bincount(const int* __restrict__ dst,
                                                  int* __restrict__ bktcnt,
                                                  int E, int nblk) {
    __shared__ int cnt[NRANGE];
    if (threadIdx.x < NRANGE) cnt[threadIdx.x] = 0;
    __syncthreads();
    int b0 = blockIdx.x * EB;
#pragma unroll
    for (int j = 0; j < 4; ++j) {
        int e = b0 + j * 256 + threadIdx.x;
        if (e < E) atomicAdd(&cnt[dst[e] / RS], 1);
    }
    __syncthreads();
    if (threadIdx.x < NRANGE)
        bktcnt[threadIdx.x * nblk + blockIdx.x] = cnt[threadIdx.x];
}

// exclusive scan (verified rounds 6-10); safe with out==in
__global__ __launch_bounds__(256) void k_scan_block(const int* __restrict__ in,
                                                    int* __restrict__ outp,
                                                    int* __restrict__ bsum, int n) {
    __shared__ int sh[256];
    int t = threadIdx.x, g = blockIdx.x * 256 + t;
    int v = (g < n) ? in[g] : 0;
    sh[t] = v; __syncthreads();
    for (int off = 1; off < 256; off <<= 1) {
        int a = (t >= off) ? sh[t - off] : 0;
        __syncthreads();
        sh[t] += a;
        __syncthreads();
    }
    if (g < n) outp[g] = sh[t] - v;
    if (t == 255) bsum[blockIdx.x] = sh[255];
}

__global__ __launch_bounds__(512) void k_scan_tops(int* __restrict__ bsum,
                                                   int* __restrict__ outp,
                                                   int nb, int n) {
    __shared__ int sh[512];
    int t = threadIdx.x;
    int v = (t < nb) ? bsum[t] : 0;
    sh[t] = v; __syncthreads();
    for (int off = 1; off < 512; off <<= 1) {
        int a = (t >= off) ? sh[t - off] : 0;
        __syncthreads();
        sh[t] += a;
        __syncthreads();
    }
    if (t < nb) bsum[t] = sh[t] - v;
    if (t == 511) outp[n] = sh[511];
}

__global__ __launch_bounds__(256) void k_scan_add(int* __restrict__ outp,
                                                  const int* __restrict__ bsum, int n) {
    int i = blockIdx.x * 256 + threadIdx.x;
    if (i < n) outp[i] += bsum[i >> 8];
}

// write each edge once into its bucket at an exact, block-reserved slot
__global__ __launch_bounds__(256) void k_binfill(const int* __restrict__ src,
                                                 const int* __restrict__ dst,
                                                 const float* __restrict__ ew,
                                                 const int* __restrict__ bktcnt,
                                                 int* __restrict__ bpack,
                                                 float* __restrict__ bew,
                                                 int E, int nblk) {
    __shared__ int base[NRANGE];
    if (threadIdx.x < NRANGE)
        base[threadIdx.x] = bktcnt[threadIdx.x * nblk + blockIdx.x];
    __syncthreads();
    int b0 = blockIdx.x * EB;
#pragma unroll
    for (int j = 0; j < 4; ++j) {
        int e = b0 + j * 256 + threadIdx.x;
        if (e < E) {
            int d = dst[e];
            int r = d / RS;
            int pos = atomicAdd(&base[r], 1);          // LDS only
            bpack[pos] = (src[e] << 12) | (d - r * RS);
            bew[pos] = ew[e];
        }
    }
}

// per-(range, slice-of-bucket) LDS histogram; reads ONLY its bucket
__global__ __launch_bounds__(256) void k_hist2(const int* __restrict__ bpack,
                                               const int* __restrict__ bktcnt,
                                               int* __restrict__ partials,
                                               int E, int nblk) {
    __shared__ int hist[RS];
    int r = blockIdx.x >> 3, s = blockIdx.x & (NS2 - 1);
    for (int t = threadIdx.x; t < RS; t += 256) hist[t] = 0;
    __syncthreads();
    int b0 = bktcnt[r * nblk];
    int b1 = (r == NRANGE - 1) ? E : bktcnt[(r + 1) * nblk];
    int len = b1 - b0, ss = (len + NS2 - 1) / NS2;
    int cs = b0 + s * ss, ce = min(cs + ss, b1);
    for (int j = cs + threadIdx.x; j < ce; j += 256)
        atomicAdd(&hist[bpack[j] & 4095], 1);
    __syncthreads();
    int* pp = partials + (size_t)(r * NS2 + s) * RS;
    for (int t = threadIdx.x; t < RS; t += 256) pp[t] = hist[t];
}

__global__ __launch_bounds__(256) void k_sumdeg(const int* __restrict__ partials,
                                                int* __restrict__ ideg, int n) {
    int d = blockIdx.x * 256 + threadIdx.x;
    if (d >= n) return;
    int r = d / RS, b = d - r * RS;
    const int* p = partials + (size_t)(r * NS2) * RS + b;
    int acc = 0;
#pragma unroll
    for (int s = 0; s < NS2; ++s) acc += p[s * RS];
    ideg[d] = acc;
}

// per-slice counts -> exact slot starts
__global__ __launch_bounds__(256) void k_slicecur(int* __restrict__ partials,
                                                  const int* __restrict__ rowptr, int n) {
    int d = blockIdx.x * 256 + threadIdx.x;
    if (d >= n) return;
    int r = d / RS, b = d - r * RS;
    int* p = partials + (size_t)(r * NS2) * RS + b;
    int run = rowptr[d];
#pragma unroll
    for (int s = 0; s < NS2; ++s) {
        int c = p[s * RS];
        p[s * RS] = run;
        run += c;
    }
}

// place edges at exact csr positions; reads only its bucket slice
__global__ __launch_bounds__(256) void k_fill3(const int* __restrict__ bpack,
                                               const float* __restrict__ bew,
                                               const int* __restrict__ bktcnt,
                                               const int* __restrict__ partials,
                                               int2* __restrict__ csr,
                                               int E, int nblk) {
    __shared__ int cur[RS];
    int r = blockIdx.x >> 3, s = blockIdx.x & (NS2 - 1);
    const int* cp = partials + (size_t)(r * NS2 + s) * RS;
    for (int t = threadIdx.x; t < RS; t += 256) cur[t] = cp[t];
    __syncthreads();
    int b0 = bktcnt[r * nblk];
    int b1 = (r == NRANGE - 1) ? E : bktcnt[(r + 1) * nblk];
    int len = b1 - b0, ss = (len + NS2 - 1) / NS2;
    int cs = b0 + s * ss, ce = min(cs + ss, b1);
    for (int j = cs + threadIdx.x; j < ce; j += 256) {
        int p = bpack[j];
        int pos = atomicAdd(&cur[p & 4095], 1);       // LDS only
        csr[pos] = make_int2(p >> 12, __float_as_int(bew[j]));
    }
}

// dinv[d] = rsqrt(1 + sum ew over csr row d)
__global__ __launch_bounds__(256) void k_wdeg(const int2* __restrict__ csr,
                                              const int* __restrict__ rowptr,
                                              float* __restrict__ dinv, int n) {
    int tid = blockIdx.x * 256 + threadIdx.x;
    int d = tid >> 4, f = tid & 15;
    if (d >= n) return;
    int e0 = rowptr[d], e1 = rowptr[d + 1];
    float w = 0.0f;
    for (int j = e0 + f; j < e1; j += 16) w += __int_as_float(csr[j].y);
#pragma unroll
    for (int o = 8; o; o >>= 1) w += __shfl_xor(w, o, 16);
    if (f == 0) dinv[d] = rsqrtf(1.0f + w);
}

// h = x @ W1 (verified). Coalesced float4 staging; conflict-free W1 layout.
__global__ __launch_bounds__(256) void k_gemm1(const float* __restrict__ x,
                                               const float* __restrict__ w1,
                                               float* __restrict__ h) {
    __shared__ float xs[16 * XPAD];
    __shared__ float wt[NF * NH];
    for (int t = threadIdx.x; t < NF * NH; t += 256) {
        int k = t >> 4, f = t & 15;
        wt[(k >> 2) * 64 + (f << 2) + (k & 3)] = w1[t];
    }
    const float4* xsrc = (const float4*)(x + (size_t)blockIdx.x * 16 * NF);
#pragma unroll
    for (int s = 0; s < 8; ++s) {
        int idx = s * 256 + threadIdx.x;
        int row = idx >> 7, col4 = idx & 127;
        float4 v = xsrc[idx];
        float* p = &xs[row * XPAD + col4 * 4];
        p[0] = v.x; p[1] = v.y; p[2] = v.z; p[3] = v.w;
    }
    __syncthreads();
    int r = threadIdx.x >> 4, f = threadIdx.x & 15;
    const float4* xr = (const float4*)&xs[r * XPAD];
    const float4* wr = (const float4*)&wt[f << 2];
    float acc = 0.0f;
#pragma unroll 8
    for (int k4 = 0; k4 < NF / 4; ++k4) {
        float4 a = xr[k4], b = wr[k4 * 16];
        acc = fmaf(a.x, b.x, acc);
        acc = fmaf(a.y, b.y, acc);
        acc = fmaf(a.z, b.z, acc);
        acc = fmaf(a.w, b.w, acc);
    }
    h[(size_t)(blockIdx.x * 16 + r) * NH + f] = acc;
}

// out[d] = in[d]*dinv[d]^2 + sum in[s]*dinv[s]*ew*dinv[d]
__global__ __launch_bounds__(256) void k_gather(const float* __restrict__ in,
                                                const float* __restrict__ dinv,
                                                const int* __restrict__ rowptr,
                                                const int2* __restrict__ csr,
                                                float* __restrict__ out, int n) {
    int tid = blockIdx.x * 256 + threadIdx.x;
    int d = tid >> 4, f = tid & 15;
    if (d >= n) return;
    float di = dinv[d];
    float acc = in[tid] * di * di;
    int e0 = rowptr[d], e1 = rowptr[d + 1];
    for (int j = e0; j < e1; ++j) {
        int2 ent = csr[j];
        float nrm = dinv[ent.x] * __int_as_float(ent.y) * di;
        acc = fmaf(in[ent.x * NH + f], nrm, acc);
    }
    out[tid] = acc;
}

__global__ __launch_bounds__(256) void k_biasrelu(float* __restrict__ o1,
                                                  const float* __restrict__ b1, int n16) {
    int tid = blockIdx.x * 256 + threadIdx.x;
    if (tid < n16) o1[tid] = fmaxf(o1[tid] + b1[tid & 15], 0.0f);
}

__global__ __launch_bounds__(256) void k_out(const float* __restrict__ agg,
                                             const float* __restrict__ w2,
                                             const float* __restrict__ b2,
                                             float* __restrict__ out, int n) {
    __shared__ float w2s[NH * 40];
    __shared__ float b2s[40];
    for (int t = threadIdx.x; t < NH * 40; t += 256) w2s[t] = w2[t];
    if (threadIdx.x < 40) b2s[threadIdx.x] = b2[threadIdx.x];
    __syncthreads();
    int i = blockIdx.x * 256 + threadIdx.x;
    if (i >= n) return;
    float v[NH];
    const float4* ap = (const float4*)(agg + (size_t)i * NH);
#pragma unroll
    for (int m = 0; m < 4; ++m) {
        float4 t4 = ap[m];
        v[4 * m] = t4.x; v[4 * m + 1] = t4.y; v[4 * m + 2] = t4.z; v[4 * m + 3] = t4.w;
    }
    float z[40];
#pragma unroll
    for (int c = 0; c < 40; ++c) {
        float a = b2s[c];
#pragma unroll
        for (int ff = 0; ff < NH; ++ff) a = fmaf(v[ff], w2s[ff * 40 + c], a);
        z[c] = a;
    }
    float mx = z[0];
#pragma unroll
    for (int c = 1; c < 40; ++c) mx = fmaxf(mx, z[c]);
    float sum = 0.0f;
#pragma unroll
    for (int c = 0; c < 40; ++c) sum += expf(z[c] - mx);
    float ls = mx + logf(sum);
    float4* op = (float4*)(out + (size_t)i * 40);
#pragma unroll
    for (int m = 0; m < 10; ++m) {
        float4 o;
        o.x = z[4 * m] - ls; o.y = z[4 * m + 1] - ls;
        o.z = z[4 * m + 2] - ls; o.w = z[4 * m + 3] - ls;
        op[m] = o;
    }
}

extern "C" void kernel_launch(void* const* d_in, const int* in_sizes, int n_in,
                              void* d_out, int out_size, void* d_ws, size_t ws_size,
                              hipStream_t stream) {
    const float* x  = (const float*)d_in[0];
    const int*   ei = (const int*)d_in[1];
    const float* ew = (const float*)d_in[2];
    const float* w1 = (const float*)d_in[3];
    const float* b1 = (const float*)d_in[4];
    const float* w2 = (const float*)d_in[5];
    const float* b2 = (const float*)d_in[6];
    float* out = (float*)d_out;

    int n = in_sizes[0] / NF;      // 100000 (= NRANGE*RS)
    int E = in_sizes[2];           // 3200000
    const int* src = ei;
    const int* dst = ei + E;

    float* ws       = (float*)d_ws;
    float* dinv     = ws;                       // n
    int*   ideg     = (int*)(ws + 100000);      // n
    int*   bsum     = (int*)(ws + 200000);      // 1024
    int*   rowptr   = (int*)(ws + 201024);      // n+1
    int*   bsum2    = (int*)(ws + 301056);      // 1024
    int*   bktcnt   = (int*)(ws + 302080);      // 100032, scanned in place
    int*   partials = (int*)(ws + 402112);      // NS2*n
    int2*  csr      = (int2*)(ws + 1202112);    // 2*E ints
    int*   bpack    = (int*)(ws + 7602112);     // E
    float* bew      = ws + 10802112;            // E
    float* h        = ws + 7602112;             // overlays bpack (dead)
    float* o1       = ws + 9202112;             // overlays bpack (dead)

    int nblk  = (E + EB - 1) / EB;              // 3125 bin blocks
    int ncnt  = NRANGE * nblk;                  // 100000 counts
    int nb_c  = (ncnt + 255) / 256;             // 391
    int nb_n  = (n + 255) / 256;                // 391
    int nb_nf = (n * NH + 255) / 256;           // 6250

    // 1) bin counts + exact bases (scan in place)
    k_bincount<<<nblk, 256, 0, stream>>>(dst, bktcnt, E, nblk);
    k_scan_block<<<nb_c, 256, 0, stream>>>(bktcnt, bktcnt, bsum2, ncnt);
    k_scan_tops<<<1, 512, 0, stream>>>(bsum2, bktcnt, nb_c, ncnt);
    k_scan_add<<<nb_c, 256, 0, stream>>>(bktcnt, bsum2, ncnt);
    // 2) bin edges (each edge written once)
    k_binfill<<<nblk, 256, 0, stream>>>(src, dst, ew, bktcnt, bpack, bew, E, nblk);
    // 3) per-range hist -> rowptr -> exact CSR
    k_hist2<<<NRANGE * NS2, 256, 0, stream>>>(bpack, bktcnt, partials, E, nblk);
    k_sumdeg<<<nb_n, 256, 0, stream>>>(partials, ideg, n);
    k_scan_block<<<nb_n, 256, 0, stream>>>(ideg, rowptr, bsum, n);
    k_scan_tops<<<1, 512, 0, stream>>>(bsum, rowptr, nb_n, n);
    k_scan_add<<<nb_n, 256, 0, stream>>>(rowptr, bsum, n);
    k_slicecur<<<nb_n, 256, 0, stream>>>(partials, rowptr, n);
    k_fill3<<<NRANGE * NS2, 256, 0, stream>>>(bpack, bew, bktcnt, partials, csr, E, nblk);
    // 4) GCN pipeline (verified)
    k_wdeg<<<nb_nf, 256, 0, stream>>>(csr, rowptr, dinv, n);
    k_gemm1<<<n / 16, 256, 0, stream>>>(x, w1, h);
    k_gather<<<nb_nf, 256, 0, stream>>>(h, dinv, rowptr, csr, o1, n);
    k_biasrelu<<<nb_nf, 256, 0, stream>>>(o1, b1, n * NH);
    k_gather<<<nb_nf, 256, 0, stream>>>(o1, dinv, rowptr, csr, h, n);
    k_out<<<nb_n, 256, 0, stream>>>(h, w2, b2, out, n);
}

// Round 13
// 396.395 us; speedup vs baseline: 1.8621x; 1.0451x over previous
//
#include <hip/hip_runtime.h>

// GCN 2-layer. Round-12: 414us total; harness fills mask top-5 (ws=800MB).
// This round: (1) NS2 8->32 -- hist2/fill3 were 256-block grids = 1 blk/CU,
// the exact round-9 latency trap (11.5% occ); now 1024 blocks. (2) binfill
// writes ONE int2 scatter (was two 4B streams = 2 dirty sectors/edge).
// (3) biasrelu fused into gather #1 epilogue. Zero global atomics still.

#define NF 512
#define NH 16
#define NRANGE 32
#define NS2 32
#define RS 3125           // nodes per range = 100000/32
#define EB 1024           // edges per bin block
#define XPAD 520

// ---- ws layout (4B units), ~52.8 MB of the 800 MB ws ----
// dinv @0 (100000) | ideg @100000 (100000) | bsum @200000 (1024)
// rowptr @201024 (100001) | bsum2 @301056 (1024)
// bktcnt @302080 (100032, scanned in place)
// partials @402112 (NRANGE*NS2*RS = 3.2M)
// csr int2 @3602112 (2E) | bin int2 @10002112 (2E, dead after fill3)
// h @10002112 overlays bin | o1 @11602112 overlays bin

__global__ __launch_bounds__(256) void k_bincount(const int* __restrict__ dst,
                                                  int* __restrict__ bktcnt,
                                                  int E, int nblk) {
    __shared__ int cnt[NRANGE];
    if (threadIdx.x < NRANGE) cnt[threadIdx.x] = 0;
    __syncthreads();
    int b0 = blockIdx.x * EB;
#pragma unroll
    for (int j = 0; j < 4; ++j) {
        int e = b0 + j * 256 + threadIdx.x;
        if (e < E) atomicAdd(&cnt[dst[e] / RS], 1);
    }
    __syncthreads();
    if (threadIdx.x < NRANGE)
        bktcnt[threadIdx.x * nblk + blockIdx.x] = cnt[threadIdx.x];
}

// exclusive scan (verified rounds 6-12); safe with out==in
__global__ __launch_bounds__(256) void k_scan_block(const int* __restrict__ in,
                                                    int* __restrict__ outp,
                                                    int* __restrict__ bsum, int n) {
    __shared__ int sh[256];
    int t = threadIdx.x, g = blockIdx.x * 256 + t;
    int v = (g < n) ? in[g] : 0;
    sh[t] = v; __syncthreads();
    for (int off = 1; off < 256; off <<= 1) {
        int a = (t >= off) ? sh[t - off] : 0;
        __syncthreads();
        sh[t] += a;
        __syncthreads();
    }
    if (g < n) outp[g] = sh[t] - v;
    if (t == 255) bsum[blockIdx.x] = sh[255];
}

__global__ __launch_bounds__(512) void k_scan_tops(int* __restrict__ bsum,
                                                   int* __restrict__ outp,
                                                   int nb, int n) {
    __shared__ int sh[512];
    int t = threadIdx.x;
    int v = (t < nb) ? bsum[t] : 0;
    sh[t] = v; __syncthreads();
    for (int off = 1; off < 512; off <<= 1) {
        int a = (t >= off) ? sh[t - off] : 0;
        __syncthreads();
        sh[t] += a;
        __syncthreads();
    }
    if (t < nb) bsum[t] = sh[t] - v;
    if (t == 511) outp[n] = sh[511];
}

__global__ __launch_bounds__(256) void k_scan_add(int* __restrict__ outp,
                                                  const int* __restrict__ bsum, int n) {
    int i = blockIdx.x * 256 + threadIdx.x;
    if (i < n) outp[i] += bsum[i >> 8];
}

// write each edge once into its bucket: ONE int2 scatter per edge
__global__ __launch_bounds__(256) void k_binfill(const int* __restrict__ src,
                                                 const int* __restrict__ dst,
                                                 const float* __restrict__ ew,
                                                 const int* __restrict__ bktcnt,
                                                 int2* __restrict__ bin,
                                                 int E, int nblk) {
    __shared__ int base[NRANGE];
    if (threadIdx.x < NRANGE)
        base[threadIdx.x] = bktcnt[threadIdx.x * nblk + blockIdx.x];
    __syncthreads();
    int b0 = blockIdx.x * EB;
#pragma unroll
    for (int j = 0; j < 4; ++j) {
        int e = b0 + j * 256 + threadIdx.x;
        if (e < E) {
            int d = dst[e];
            int r = d / RS;
            int pos = atomicAdd(&base[r], 1);          // LDS only
            bin[pos] = make_int2((src[e] << 12) | (d - r * RS),
                                 __float_as_int(ew[e]));
        }
    }
}

// per-(range, slice) LDS histogram; reads only its bucket slice
__global__ __launch_bounds__(256) void k_hist2(const int2* __restrict__ bin,
                                               const int* __restrict__ bktcnt,
                                               int* __restrict__ partials,
                                               int E, int nblk) {
    __shared__ int hist[RS];
    int r = blockIdx.x >> 5, s = blockIdx.x & (NS2 - 1);
    for (int t = threadIdx.x; t < RS; t += 256) hist[t] = 0;
    __syncthreads();
    int b0 = bktcnt[r * nblk];
    int b1 = (r == NRANGE - 1) ? E : bktcnt[(r + 1) * nblk];
    int len = b1 - b0, ss = (len + NS2 - 1) / NS2;
    int cs = b0 + s * ss, ce = min(cs + ss, b1);
    for (int j = cs + threadIdx.x; j < ce; j += 256)
        atomicAdd(&hist[bin[j].x & 4095], 1);
    __syncthreads();
    int* pp = partials + (size_t)(r * NS2 + s) * RS;
    for (int t = threadIdx.x; t < RS; t += 256) pp[t] = hist[t];
}

__global__ __launch_bounds__(256) void k_sumdeg(const int* __restrict__ partials,
                                                int* __restrict__ ideg, int n) {
    int d = blockIdx.x * 256 + threadIdx.x;
    if (d >= n) return;
    int r = d / RS, b = d - r * RS;
    const int* p = partials + (size_t)(r * NS2) * RS + b;
    int acc = 0;
#pragma unroll
    for (int s = 0; s < NS2; ++s) acc += p[s * RS];
    ideg[d] = acc;
}

// per-slice counts -> exact slot starts
__global__ __launch_bounds__(256) void k_slicecur(int* __restrict__ partials,
                                                  const int* __restrict__ rowptr, int n) {
    int d = blockIdx.x * 256 + threadIdx.x;
    if (d >= n) return;
    int r = d / RS, b = d - r * RS;
    int* p = partials + (size_t)(r * NS2) * RS + b;
    int run = rowptr[d];
#pragma unroll
    for (int s = 0; s < NS2; ++s) {
        int c = p[s * RS];
        p[s * RS] = run;
        run += c;
    }
}

// place edges at exact csr positions; reads only its bucket slice
__global__ __launch_bounds__(256) void k_fill3(const int2* __restrict__ bin,
                                               const int* __restrict__ bktcnt,
                                               const int* __restrict__ partials,
                                               int2* __restrict__ csr,
                                               int E, int nblk) {
    __shared__ int cur[RS];
    int r = blockIdx.x >> 5, s = blockIdx.x & (NS2 - 1);
    const int* cp = partials + (size_t)(r * NS2 + s) * RS;
    for (int t = threadIdx.x; t < RS; t += 256) cur[t] = cp[t];
    __syncthreads();
    int b0 = bktcnt[r * nblk];
    int b1 = (r == NRANGE - 1) ? E : bktcnt[(r + 1) * nblk];
    int len = b1 - b0, ss = (len + NS2 - 1) / NS2;
    int cs = b0 + s * ss, ce = min(cs + ss, b1);
    for (int j = cs + threadIdx.x; j < ce; j += 256) {
        int2 p2 = bin[j];
        int pos = atomicAdd(&cur[p2.x & 4095], 1);    // LDS only
        csr[pos] = make_int2(p2.x >> 12, p2.y);
    }
}

// dinv[d] = rsqrt(1 + sum ew over csr row d)
__global__ __launch_bounds__(256) void k_wdeg(const int2* __restrict__ csr,
                                              const int* __restrict__ rowptr,
                                              float* __restrict__ dinv, int n) {
    int tid = blockIdx.x * 256 + threadIdx.x;
    int d = tid >> 4, f = tid & 15;
    if (d >= n) return;
    int e0 = rowptr[d], e1 = rowptr[d + 1];
    float w = 0.0f;
    for (int j = e0 + f; j < e1; j += 16) w += __int_as_float(csr[j].y);
#pragma unroll
    for (int o = 8; o; o >>= 1) w += __shfl_xor(w, o, 16);
    if (f == 0) dinv[d] = rsqrtf(1.0f + w);
}

// h = x @ W1 (verified). Coalesced float4 staging; conflict-free W1 layout.
__global__ __launch_bounds__(256) void k_gemm1(const float* __restrict__ x,
                                               const float* __restrict__ w1,
                                               float* __restrict__ h) {
    __shared__ float xs[16 * XPAD];
    __shared__ float wt[NF * NH];
    for (int t = threadIdx.x; t < NF * NH; t += 256) {
        int k = t >> 4, f = t & 15;
        wt[(k >> 2) * 64 + (f << 2) + (k & 3)] = w1[t];
    }
    const float4* xsrc = (const float4*)(x + (size_t)blockIdx.x * 16 * NF);
#pragma unroll
    for (int s = 0; s < 8; ++s) {
        int idx = s * 256 + threadIdx.x;
        int row = idx >> 7, col4 = idx & 127;
        float4 v = xsrc[idx];
        float* p = &xs[row * XPAD + col4 * 4];
        p[0] = v.x; p[1] = v.y; p[2] = v.z; p[3] = v.w;
    }
    __syncthreads();
    int r = threadIdx.x >> 4, f = threadIdx.x & 15;
    const float4* xr = (const float4*)&xs[r * XPAD];
    const float4* wr = (const float4*)&wt[f << 2];
    float acc = 0.0f;
#pragma unroll 8
    for (int k4 = 0; k4 < NF / 4; ++k4) {
        float4 a = xr[k4], b = wr[k4 * 16];
        acc = fmaf(a.x, b.x, acc);
        acc = fmaf(a.y, b.y, acc);
        acc = fmaf(a.z, b.z, acc);
        acc = fmaf(a.w, b.w, acc);
    }
    h[(size_t)(blockIdx.x * 16 + r) * NH + f] = acc;
}

// layer-1 gather with fused bias+relu: out = relu(agg + b1[f])
__global__ __launch_bounds__(256) void k_gather_relu(const float* __restrict__ in,
                                                     const float* __restrict__ dinv,
                                                     const int* __restrict__ rowptr,
                                                     const int2* __restrict__ csr,
                                                     const float* __restrict__ b1,
                                                     float* __restrict__ out, int n) {
    int tid = blockIdx.x * 256 + threadIdx.x;
    int d = tid >> 4, f = tid & 15;
    if (d >= n) return;
    float di = dinv[d];
    float acc = in[tid] * di * di;
    int e0 = rowptr[d], e1 = rowptr[d + 1];
    for (int j = e0; j < e1; ++j) {
        int2 ent = csr[j];
        float nrm = dinv[ent.x] * __int_as_float(ent.y) * di;
        acc = fmaf(in[ent.x * NH + f], nrm, acc);
    }
    out[tid] = fmaxf(acc + b1[f], 0.0f);
}

// layer-2 gather (plain)
__global__ __launch_bounds__(256) void k_gather(const float* __restrict__ in,
                                                const float* __restrict__ dinv,
                                                const int* __restrict__ rowptr,
                                                const int2* __restrict__ csr,
                                                float* __restrict__ out, int n) {
    int tid = blockIdx.x * 256 + threadIdx.x;
    int d = tid >> 4, f = tid & 15;
    if (d >= n) return;
    float di = dinv[d];
    float acc = in[tid] * di * di;
    int e0 = rowptr[d], e1 = rowptr[d + 1];
    for (int j = e0; j < e1; ++j) {
        int2 ent = csr[j];
        float nrm = dinv[ent.x] * __int_as_float(ent.y) * di;
        acc = fmaf(in[ent.x * NH + f], nrm, acc);
    }
    out[tid] = acc;
}

__global__ __launch_bounds__(256) void k_out(const float* __restrict__ agg,
                                             const float* __restrict__ w2,
                                             const float* __restrict__ b2,
                                             float* __restrict__ out, int n) {
    __shared__ float w2s[NH * 40];
    __shared__ float b2s[40];
    for (int t = threadIdx.x; t < NH * 40; t += 256) w2s[t] = w2[t];
    if (threadIdx.x < 40) b2s[threadIdx.x] = b2[threadIdx.x];
    __syncthreads();
    int i = blockIdx.x * 256 + threadIdx.x;
    if (i >= n) return;
    float v[NH];
    const float4* ap = (const float4*)(agg + (size_t)i * NH);
#pragma unroll
    for (int m = 0; m < 4; ++m) {
        float4 t4 = ap[m];
        v[4 * m] = t4.x; v[4 * m + 1] = t4.y; v[4 * m + 2] = t4.z; v[4 * m + 3] = t4.w;
    }
    float z[40];
#pragma unroll
    for (int c = 0; c < 40; ++c) {
        float a = b2s[c];
#pragma unroll
        for (int ff = 0; ff < NH; ++ff) a = fmaf(v[ff], w2s[ff * 40 + c], a);
        z[c] = a;
    }
    float mx = z[0];
#pragma unroll
    for (int c = 1; c < 40; ++c) mx = fmaxf(mx, z[c]);
    float sum = 0.0f;
#pragma unroll
    for (int c = 0; c < 40; ++c) sum += expf(z[c] - mx);
    float ls = mx + logf(sum);
    float4* op = (float4*)(out + (size_t)i * 40);
#pragma unroll
    for (int m = 0; m < 10; ++m) {
        float4 o;
        o.x = z[4 * m] - ls; o.y = z[4 * m + 1] - ls;
        o.z = z[4 * m + 2] - ls; o.w = z[4 * m + 3] - ls;
        op[m] = o;
    }
}

extern "C" void kernel_launch(void* const* d_in, const int* in_sizes, int n_in,
                              void* d_out, int out_size, void* d_ws, size_t ws_size,
                              hipStream_t stream) {
    const float* x  = (const float*)d_in[0];
    const int*   ei = (const int*)d_in[1];
    const float* ew = (const float*)d_in[2];
    const float* w1 = (const float*)d_in[3];
    const float* b1 = (const float*)d_in[4];
    const float* w2 = (const float*)d_in[5];
    const float* b2 = (const float*)d_in[6];
    float* out = (float*)d_out;

    int n = in_sizes[0] / NF;      // 100000 (= NRANGE*RS)
    int E = in_sizes[2];           // 3200000
    const int* src = ei;
    const int* dst = ei + E;

    float* ws       = (float*)d_ws;
    float* dinv     = ws;                       // n
    int*   ideg     = (int*)(ws + 100000);      // n
    int*   bsum     = (int*)(ws + 200000);      // 1024
    int*   rowptr   = (int*)(ws + 201024);      // n+1
    int*   bsum2    = (int*)(ws + 301056);      // 1024
    int*   bktcnt   = (int*)(ws + 302080);      // 100032, scanned in place
    int*   partials = (int*)(ws + 402112);      // NRANGE*NS2*RS = 3.2M
    int2*  csr      = (int2*)(ws + 3602112);    // 2*E ints
    int2*  bin      = (int2*)(ws + 10002112);   // 2*E ints, dead after fill3
    float* h        = ws + 10002112;            // overlays bin
    float* o1       = ws + 11602112;            // overlays bin

    int nblk  = (E + EB - 1) / EB;              // 3125 bin blocks
    int ncnt  = NRANGE * nblk;                  // 100000 counts
    int nb_c  = (ncnt + 255) / 256;             // 391
    int nb_n  = (n + 255) / 256;                // 391
    int nb_nf = (n * NH + 255) / 256;           // 6250

    // 1) bin counts + exact bases (scan in place)
    k_bincount<<<nblk, 256, 0, stream>>>(dst, bktcnt, E, nblk);
    k_scan_block<<<nb_c, 256, 0, stream>>>(bktcnt, bktcnt, bsum2, ncnt);
    k_scan_tops<<<1, 512, 0, stream>>>(bsum2, bktcnt, nb_c, ncnt);
    k_scan_add<<<nb_c, 256, 0, stream>>>(bktcnt, bsum2, ncnt);
    // 2) bin edges (each edge written once, single int2 scatter)
    k_binfill<<<nblk, 256, 0, stream>>>(src, dst, ew, bktcnt, bin, E, nblk);
    // 3) per-range hist -> rowptr -> exact CSR (1024-block grids)
    k_hist2<<<NRANGE * NS2, 256, 0, stream>>>(bin, bktcnt, partials, E, nblk);
    k_sumdeg<<<nb_n, 256, 0, stream>>>(partials, ideg, n);
    k_scan_block<<<nb_n, 256, 0, stream>>>(ideg, rowptr, bsum, n);
    k_scan_tops<<<1, 512, 0, stream>>>(bsum, rowptr, nb_n, n);
    k_scan_add<<<nb_n, 256, 0, stream>>>(rowptr, bsum, n);
    k_slicecur<<<nb_n, 256, 0, stream>>>(partials, rowptr, n);
    k_fill3<<<NRANGE * NS2, 256, 0, stream>>>(bin, bktcnt, partials, csr, E, nblk);
    // 4) GCN pipeline (verified)
    k_wdeg<<<nb_nf, 256, 0, stream>>>(csr, rowptr, dinv, n);
    k_gemm1<<<n / 16, 256, 0, stream>>>(x, w1, h);
    k_gather_relu<<<nb_nf, 256, 0, stream>>>(h, dinv, rowptr, csr, b1, o1, n);
    k_gather<<<nb_nf, 256, 0, stream>>>(o1, dinv, rowptr, csr, h, n);
    k_out<<<nb_n, 256, 0, stream>>>(h, w2, b2, out, n);
}